// Round 2
// baseline (1596.398 us; speedup 1.0000x reference)
//
#include <hip/hip_runtime.h>
#include <hip/hip_bf16.h>

#define DEV static __device__ __forceinline__

typedef short bfx8 __attribute__((ext_vector_type(8)));   // 8 bf16 in 4 VGPRs (guide §3)
typedef float fx4  __attribute__((ext_vector_type(4)));

DEV float bf2f(__hip_bfloat16 h) { return __bfloat162float(h); }
DEV __hip_bfloat16 f2bf(float f) { return __float2bfloat16(f); }
DEV float uLO(unsigned u) { return __uint_as_float(u << 16); }
DEV float uHI(unsigned u) { return __uint_as_float(u & 0xffff0000u); }

DEV float wave_sum(float v) {
#pragma unroll
  for (int o = 32; o; o >>= 1) v += __shfl_xor(v, o, 64);
  return v;
}
DEV float wave_max(float v) {
#pragma unroll
  for (int o = 32; o; o >>= 1) v = fmaxf(v, __shfl_xor(v, o, 64));
  return v;
}

#define GLD_LDS16(gp, lp) __builtin_amdgcn_global_load_lds( \
    (__attribute__((address_space(1))) void*)(gp),          \
    (__attribute__((address_space(3))) void*)(lp), 16, 0, 0)

// -------- transpose+convert: src fp32 [R][C] -> dst bf16 [C][R], batch z ----
__global__ __launch_bounds__(256) void transpose_k(
    const float* __restrict__ src, __hip_bfloat16* __restrict__ dst,
    int R, int C)
{
  __shared__ float tile[32][33];
  size_t off = (size_t)blockIdx.z * R * C;
  src += off; dst += off;
  int c0 = blockIdx.x * 32, r0 = blockIdx.y * 32;
#pragma unroll
  for (int i = 0; i < 32; i += 8)
    tile[threadIdx.y + i][threadIdx.x] =
        src[(size_t)(r0 + threadIdx.y + i) * C + c0 + threadIdx.x];
  __syncthreads();
#pragma unroll
  for (int i = 0; i < 32; i += 8)
    dst[(size_t)(c0 + threadIdx.y + i) * R + r0 + threadIdx.x] =
        f2bf(tile[threadIdx.x][threadIdx.y + i]);
}

// ---------------- GEMM: C = A[M,K] x B  (B given transposed: BT[N,K]) ------
// 128x128 tile, 4 waves, each wave 64x64 via 4x4 mfma_f32_16x16x32_bf16.
enum { EPI_STORE = 0, EPI_GELU = 1, EPI_RESADD = 2, EPI_MOE = 3, EPI_HEAD = 4 };

template <int MODE>
__global__ __launch_bounds__(256) void gemm_bt(
    const __hip_bfloat16* __restrict__ A,    // [M,K]
    const __hip_bfloat16* __restrict__ BT,   // [zt][N,K]
    const float* __restrict__ bias,          // [zt][N] fp32
    int M, int N, int K, int splitK, int taskBase,
    long long strideBz, long long strideBiasz,
    __hip_bfloat16* __restrict__ Cb, float* __restrict__ Cf,
    const float* __restrict__ combine, const int* __restrict__ valid)
{
  __shared__ __hip_bfloat16 sA[128 * 32];  // [m][k]
  __shared__ __hip_bfloat16 sB[128 * 32];  // [n][k]
  const int tid = threadIdx.x;
  const int wave = tid >> 6, lane = tid & 63;
  const int quad = lane >> 4, l16 = lane & 15;
  const int z = blockIdx.z;
  const int zt = z / splitK;
  const int kc = z - zt * splitK;
  const int task = taskBase + zt;
  const int Ksub = K / splitK;
  const int kbeg = kc * Ksub;
  const __hip_bfloat16* Bz = BT + (size_t)zt * strideBz;
  const float* biasz = bias + (size_t)zt * strideBiasz;
  const int m0 = blockIdx.y * 128, n0 = blockIdx.x * 128;
  const int wm = (wave >> 1) * 64, wn = (wave & 1) * 64;

  fx4 acc[4][4];
#pragma unroll
  for (int i = 0; i < 4; ++i)
#pragma unroll
    for (int j = 0; j < 4; ++j) acc[i][j] = (fx4){0.f, 0.f, 0.f, 0.f};

  // staging: chunk c covers row c>>2, k-seg (c&3)*8 ; LDS dest = c*8 elems
  // (wave-uniform base + lane*16B — matches m104/m108 constraint)
  const int c0 = tid, c1 = tid + 256;
  int gm0 = m0 + (c0 >> 2); if (gm0 > M - 1) gm0 = M - 1;
  int gm1 = m0 + (c1 >> 2); if (gm1 > M - 1) gm1 = M - 1;
  const int ak0 = (c0 & 3) * 8, ak1 = (c1 & 3) * 8;
  const __hip_bfloat16* pa0 = A + (size_t)gm0 * K + kbeg + ak0;
  const __hip_bfloat16* pa1 = A + (size_t)gm1 * K + kbeg + ak1;
  const __hip_bfloat16* pb0 = Bz + (size_t)(n0 + (c0 >> 2)) * K + kbeg + ak0;
  const __hip_bfloat16* pb1 = Bz + (size_t)(n0 + (c1 >> 2)) * K + kbeg + ak1;

  for (int kk = 0; kk < Ksub; kk += 32) {
    GLD_LDS16(pa0 + kk, &sA[c0 * 8]);
    GLD_LDS16(pa1 + kk, &sA[c1 * 8]);
    GLD_LDS16(pb0 + kk, &sB[c0 * 8]);
    GLD_LDS16(pb1 + kk, &sB[c1 * 8]);
    __syncthreads();   // drains vmcnt -> LDS writes visible
    bfx8 af[4], bfr[4];
#pragma unroll
    for (int i = 0; i < 4; ++i)
      af[i] = *(const bfx8*)(&sA[(wm + i * 16 + l16) * 32 + quad * 8]);
#pragma unroll
    for (int j = 0; j < 4; ++j)
      bfr[j] = *(const bfx8*)(&sB[(wn + j * 16 + l16) * 32 + quad * 8]);
#pragma unroll
    for (int i = 0; i < 4; ++i)
#pragma unroll
      for (int j = 0; j < 4; ++j)
        acc[i][j] = __builtin_amdgcn_mfma_f32_16x16x32_bf16(af[i], bfr[j], acc[i][j], 0, 0, 0);
    __syncthreads();
  }

  // epilogue: C/D layout col=lane&15, row=quad*4+reg (m89-verified)
  const int mb = m0 + wm + quad * 4;
  const int nb = n0 + wn + l16;
#pragma unroll
  for (int i = 0; i < 4; ++i) {
#pragma unroll
    for (int rr = 0; rr < 4; ++rr) {
      const int m = mb + i * 16 + rr;
      if (m >= M) continue;
#pragma unroll
      for (int j = 0; j < 4; ++j) {
        const int n = nb + j * 16;
        float v = acc[i][j][rr];
        if (MODE == EPI_STORE) {
          Cb[(size_t)m * N + n] = f2bf(v + biasz[n]);
        } else if (MODE == EPI_GELU) {
          float t = v + biasz[n];
          Cb[(size_t)m * N + n] = f2bf(0.5f * t * (1.f + erff(t * 0.70710678118654752f)));
        } else if (MODE == EPI_RESADD) {
          if (kc == 0) v += biasz[n];
          atomicAdd(&Cf[(size_t)m * N + n], v);
        } else if (MODE == EPI_MOE) {
          float s = combine[m * 8 + task];
          if (s != 0.f) {
            if (kc == 0) v += biasz[n];
            atomicAdd(&Cf[(size_t)m * N + n], s * v);
          }
        } else {  // EPI_HEAD
          if (valid[task * M + m]) atomicAdd(&Cf[(size_t)m * N + n], v + biasz[n]);
        }
      }
    }
  }
}

// ---------------- attention: one block per (b,h,row-chunk of 25) ----------
__global__ __launch_bounds__(256) void attn_k(
    const __hip_bfloat16* __restrict__ qkvb, __hip_bfloat16* __restrict__ outb)
{
  __shared__ unsigned Ks[197 * 33];  // bf16 pairs, padded stride 33 words
  __shared__ unsigned Vs[197 * 33];
  __shared__ float prow[4][197];
  const int bh = blockIdx.x >> 3;
  const int chunk = blockIdx.x & 7;
  const int b = bh / 12, h = bh - b * 12;
  const int tid = threadIdx.x;
  const size_t tokBase = (size_t)b * 197;
  for (int idx = tid; idx < 197 * 32; idx += 256) {
    int j = idx >> 5, dp = idx & 31;
    const __hip_bfloat16* kp = qkvb + (tokBase + j) * 2304 + 768 + h * 64 + dp * 2;
    Ks[j * 33 + dp] = *(const unsigned*)kp;
    Vs[j * 33 + dp] = *(const unsigned*)(kp + 768);
  }
  __syncthreads();
  const int wv = tid >> 6, lane = tid & 63;
  int r1 = chunk * 25 + 25; if (r1 > 197) r1 = 197;
  for (int r = chunk * 25 + wv; r < r1; r += 4) {   // no barriers below (divergent trip counts)
    float q[64];
    const __hip_bfloat16* qp = qkvb + (tokBase + r) * 2304 + h * 64;
#pragma unroll
    for (int i8 = 0; i8 < 8; ++i8) {
      uint4 u = *(const uint4*)(qp + i8 * 8);
      q[i8*8+0]=uLO(u.x)*0.125f; q[i8*8+1]=uHI(u.x)*0.125f;
      q[i8*8+2]=uLO(u.y)*0.125f; q[i8*8+3]=uHI(u.y)*0.125f;
      q[i8*8+4]=uLO(u.z)*0.125f; q[i8*8+5]=uHI(u.z)*0.125f;
      q[i8*8+6]=uLO(u.w)*0.125f; q[i8*8+7]=uHI(u.w)*0.125f;
    }
    float sj[4];
    float mx = -3.0e38f;
#pragma unroll
    for (int t4 = 0; t4 < 4; ++t4) {
      int j = lane + t4 * 64;
      float s = -3.0e38f;
      if (j < 197) {
        s = 0.f;
        const unsigned* kr = &Ks[j * 33];
#pragma unroll
        for (int dp = 0; dp < 32; ++dp) {
          unsigned pk = kr[dp];
          s += q[2*dp] * uLO(pk) + q[2*dp+1] * uHI(pk);
        }
      }
      sj[t4] = s;
      mx = fmaxf(mx, s);
    }
    mx = wave_max(mx);
    float sum = 0.f;
#pragma unroll
    for (int t4 = 0; t4 < 4; ++t4) {
      int j = lane + t4 * 64;
      if (j < 197) { float e = __expf(sj[t4] - mx); prow[wv][j] = e; sum += e; }
    }
    sum = wave_sum(sum);
    const float inv = 1.f / sum;
    float o = 0.f;
    const int dp2 = lane >> 1;
    const int odd = lane & 1;
    for (int j = 0; j < 197; ++j) {
      unsigned pv = Vs[j * 33 + dp2];
      o += prow[wv][j] * (odd ? uHI(pv) : uLO(pv));
    }
    outb[(tokBase + r) * 768 + h * 64 + lane] = f2bf(o * inv);
  }
}

// ---------------- LayerNorm: one wave per token, fp32 in -> bf16 out -------
__global__ __launch_bounds__(256) void ln_k(
    const float* __restrict__ xf, const float* __restrict__ w,
    const float* __restrict__ b, __hip_bfloat16* __restrict__ out, int T)
{
  int wv = threadIdx.x >> 6, lane = threadIdx.x & 63;
  int t = blockIdx.x * 4 + wv;
  if (t >= T) return;
  const float* row = xf + (size_t)t * 768;
  float v[12]; float s = 0.f;
#pragma unroll
  for (int i = 0; i < 12; ++i) { v[i] = row[lane + i * 64]; s += v[i]; }
  s = wave_sum(s);
  float mean = s * (1.f / 768.f);
  float q = 0.f;
#pragma unroll
  for (int i = 0; i < 12; ++i) { float d = v[i] - mean; q += d * d; }
  q = wave_sum(q);
  float rstd = rsqrtf(q * (1.f / 768.f) + 1e-5f);
#pragma unroll
  for (int i = 0; i < 12; ++i) {
    int d = lane + i * 64;
    out[(size_t)t * 768 + d] = f2bf((v[i] - mean) * rstd * w[d] + b[d]);
  }
}

// ---------------- MoE gating: fp32 LN + logits + softmax + top-4 ----------
__global__ __launch_bounds__(256) void gate_k(
    const float* __restrict__ xf, const float* __restrict__ lw,
    const float* __restrict__ lb, const float* __restrict__ gw,
    float* __restrict__ combine, int T)
{
  int wv = threadIdx.x >> 6, lane = threadIdx.x & 63;
  int t = blockIdx.x * 4 + wv;
  if (t >= T) return;
  const float* row = xf + (size_t)t * 768;
  float v[12]; float s = 0.f;
#pragma unroll
  for (int i = 0; i < 12; ++i) { v[i] = row[lane + i * 64]; s += v[i]; }
  s = wave_sum(s);
  float mean = s * (1.f / 768.f);
  float qv = 0.f;
#pragma unroll
  for (int i = 0; i < 12; ++i) { float d = v[i] - mean; qv += d * d; }
  qv = wave_sum(qv);
  float rstd = rsqrtf(qv * (1.f / 768.f) + 1e-5f);
  float acc[8];
#pragma unroll
  for (int e = 0; e < 8; ++e) acc[e] = 0.f;
#pragma unroll
  for (int i = 0; i < 12; ++i) {
    int d = lane + i * 64;
    float xn = (v[i] - mean) * rstd * lw[d] + lb[d];
    float4 g0 = *(const float4*)(gw + (size_t)d * 8);
    float4 g1 = *(const float4*)(gw + (size_t)d * 8 + 4);
    acc[0] += xn * g0.x; acc[1] += xn * g0.y;
    acc[2] += xn * g0.z; acc[3] += xn * g0.w;
    acc[4] += xn * g1.x; acc[5] += xn * g1.y;
    acc[6] += xn * g1.z; acc[7] += xn * g1.w;
  }
#pragma unroll
  for (int e = 0; e < 8; ++e) acc[e] = wave_sum(acc[e]);
  float mx = acc[0];
#pragma unroll
  for (int e = 1; e < 8; ++e) mx = fmaxf(mx, acc[e]);
  float p[8]; float se = 0.f;
#pragma unroll
  for (int e = 0; e < 8; ++e) { p[e] = __expf(acc[e] - mx); se += p[e]; }
  float inv = 1.f / se;
#pragma unroll
  for (int e = 0; e < 8; ++e) p[e] *= inv;
  float outv[8]; bool used[8];
#pragma unroll
  for (int e = 0; e < 8; ++e) { outv[e] = 0.f; used[e] = false; }
  for (int k = 0; k < 4; ++k) {   // top-4, ties -> lowest index (matches top_k)
    int best = -1; float bv = -1.f;
#pragma unroll
    for (int e = 0; e < 8; ++e) if (!used[e] && p[e] > bv) { bv = p[e]; best = e; }
#pragma unroll
    for (int e = 0; e < 8; ++e) if (e == best) { used[e] = true; outv[e] = bv; }
  }
#pragma unroll
  for (int e = 0; e < 8; ++e) if (lane == e) combine[(size_t)t * 8 + e] = outv[e];
}

// ---------------- masks / small utils --------------------------------------
__global__ void mask_k(const int* __restrict__ sm, const int* __restrict__ am,
                       float* __restrict__ cnt, int* __restrict__ valid, int T)
{
  int t = blockIdx.x * 256 + threadIdx.x;
  if (t >= T) return;
  int a = am[t] != 0;
  float c = 0.f;
#pragma unroll
  for (int tt = 0; tt < 8; ++tt) {
    int vv = (sm[tt * T + t] != 0) & a;
    valid[tt * T + t] = vv;
    c += (float)vv;
  }
  cnt[t] = c;
}

__global__ void f2b_k(const float* __restrict__ in, __hip_bfloat16* __restrict__ out, int n) {
  int i = blockIdx.x * 256 + threadIdx.x;
  if (i < n) out[i] = f2bf(in[i]);
}
// in-place: out[i] = out[i] / (cnt[i/768] + 1e-6)
__global__ void final_k(float* __restrict__ out, const float* __restrict__ cnt, int n) {
  int i = blockIdx.x * 256 + threadIdx.x;
  if (i < n) out[i] = out[i] / (cnt[i / 768] + 1e-6f);
}

// ---------------- host ------------------------------------------------------
extern "C" void kernel_launch(void* const* d_in, const int* in_sizes, int n_in,
                              void* d_out, int out_size, void* d_ws, size_t ws_size,
                              hipStream_t stream)
{
  (void)in_sizes; (void)n_in; (void)out_size; (void)ws_size;
  const int Ttok = 8 * 197;  // 1576
  const int D = 768, HID = 3072;

  const float* x       = (const float*)d_in[0];
  const float* ln1a_w  = (const float*)d_in[1];
  const float* ln1a_b  = (const float*)d_in[2];
  const float* qkv_wa  = (const float*)d_in[3];
  const float* qkv_ba  = (const float*)d_in[4];
  const float* proj_wa = (const float*)d_in[5];
  const float* proj_ba = (const float*)d_in[6];
  const float* ln2a_w  = (const float*)d_in[7];
  const float* ln2a_b  = (const float*)d_in[8];
  const float* fc1_w   = (const float*)d_in[9];
  const float* fc1_b   = (const float*)d_in[10];
  const float* fc2_w   = (const float*)d_in[11];
  const float* fc2_b   = (const float*)d_in[12];
  const float* ln1b_w  = (const float*)d_in[13];
  const float* ln1b_b  = (const float*)d_in[14];
  const float* qkv_wb  = (const float*)d_in[15];
  const float* qkv_bb  = (const float*)d_in[16];
  const float* proj_wb = (const float*)d_in[17];
  const float* proj_bb = (const float*)d_in[18];
  const float* ln2b_w  = (const float*)d_in[19];
  const float* ln2b_b  = (const float*)d_in[20];
  const float* gate_w  = (const float*)d_in[21];
  const float* w1      = (const float*)d_in[22];
  const float* b1      = (const float*)d_in[23];
  const float* w2      = (const float*)d_in[24];
  const float* b2      = (const float*)d_in[25];
  const float* head_w  = (const float*)d_in[26];
  const float* head_b  = (const float*)d_in[27];
  const int* shared_masks = (const int*)d_in[28];
  const int* agg_mask     = (const int*)d_in[29];
  float* out           = (float*)d_out;

  char* wsp = (char*)d_ws;
  auto alloc = [&](size_t bytes) { char* p = wsp; wsp += (bytes + 255) & ~(size_t)255; return p; };
  float* xf             = (float*)alloc((size_t)Ttok * D * 4);
  __hip_bfloat16* lnb   = (__hip_bfloat16*)alloc((size_t)Ttok * D * 2);
  __hip_bfloat16* qkvb  = (__hip_bfloat16*)alloc((size_t)Ttok * 3 * D * 2);
  __hip_bfloat16* attnb = (__hip_bfloat16*)alloc((size_t)Ttok * D * 2);
  __hip_bfloat16* h1    = (__hip_bfloat16*)alloc((size_t)Ttok * HID * 2);
  float* combine        = (float*)alloc((size_t)Ttok * 8 * 4);
  float* cnt            = (float*)alloc((size_t)Ttok * 4);
  int* valid            = (int*)alloc((size_t)8 * Ttok * 4);
  __hip_bfloat16* qkvaT = (__hip_bfloat16*)alloc((size_t)D * 3 * D * 2);
  __hip_bfloat16* projaT= (__hip_bfloat16*)alloc((size_t)D * D * 2);
  __hip_bfloat16* fc1T  = (__hip_bfloat16*)alloc((size_t)D * HID * 2);
  __hip_bfloat16* fc2T  = (__hip_bfloat16*)alloc((size_t)D * HID * 2);
  __hip_bfloat16* qkvbT = (__hip_bfloat16*)alloc((size_t)D * 3 * D * 2);
  __hip_bfloat16* projbT= (__hip_bfloat16*)alloc((size_t)D * D * 2);
  __hip_bfloat16* headT = (__hip_bfloat16*)alloc((size_t)8 * D * D * 2);
  __hip_bfloat16* wT    = (__hip_bfloat16*)alloc((size_t)D * HID * 2);

  dim3 tb(32, 8);
  transpose_k<<<dim3(3*D/32, D/32, 1), tb, 0, stream>>>(qkv_wa, qkvaT, D, 3*D);
  transpose_k<<<dim3(D/32, D/32, 1),   tb, 0, stream>>>(proj_wa, projaT, D, D);
  transpose_k<<<dim3(HID/32, D/32, 1), tb, 0, stream>>>(fc1_w, fc1T, D, HID);
  transpose_k<<<dim3(D/32, HID/32, 1), tb, 0, stream>>>(fc2_w, fc2T, HID, D);
  transpose_k<<<dim3(3*D/32, D/32, 1), tb, 0, stream>>>(qkv_wb, qkvbT, D, 3*D);
  transpose_k<<<dim3(D/32, D/32, 1),   tb, 0, stream>>>(proj_wb, projbT, D, D);
  transpose_k<<<dim3(D/32, D/32, 8),   tb, 0, stream>>>(head_w, headT, D, D);

  const int nTok = Ttok * D;
  hipMemcpyAsync(xf, x, (size_t)nTok * 4, hipMemcpyDeviceToDevice, stream);
  mask_k<<<(Ttok + 255)/256, 256, 0, stream>>>(shared_masks, agg_mask, cnt, valid, Ttok);
  hipMemsetAsync(out, 0, (size_t)nTok * 4, stream);  // head accumulation buffer

  const int lnGrid = (Ttok + 3) / 4;
  dim3 g_qkv(3*D/128, 13, 1);
  dim3 g_proj(D/128, 13, 4);    // split-K x4
  dim3 g_fc1(HID/128, 13, 1);
  dim3 g_fc2(D/128, 13, 4);     // split-K x4
  dim3 g_head(D/128, 13, 8);    // z = task

  // ---- dense ViT block ----
  ln_k<<<lnGrid, 256, 0, stream>>>(xf, ln1a_w, ln1a_b, lnb, Ttok);
  gemm_bt<EPI_STORE><<<g_qkv, 256, 0, stream>>>(lnb, qkvaT, qkv_ba, Ttok, 3*D, D, 1, 0, 0, 0, qkvb, nullptr, nullptr, nullptr);
  attn_k<<<96 * 8, 256, 0, stream>>>(qkvb, attnb);
  gemm_bt<EPI_RESADD><<<g_proj, 256, 0, stream>>>(attnb, projaT, proj_ba, Ttok, D, D, 4, 0, 0, 0, nullptr, xf, nullptr, nullptr);
  ln_k<<<lnGrid, 256, 0, stream>>>(xf, ln2a_w, ln2a_b, lnb, Ttok);
  gemm_bt<EPI_GELU><<<g_fc1, 256, 0, stream>>>(lnb, fc1T, fc1_b, Ttok, HID, D, 1, 0, 0, 0, h1, nullptr, nullptr, nullptr);
  gemm_bt<EPI_RESADD><<<g_fc2, 256, 0, stream>>>(h1, fc2T, fc2_b, Ttok, D, HID, 4, 0, 0, 0, nullptr, xf, nullptr, nullptr);

  // ---- MoE ViT block ----
  ln_k<<<lnGrid, 256, 0, stream>>>(xf, ln1b_w, ln1b_b, lnb, Ttok);
  gemm_bt<EPI_STORE><<<g_qkv, 256, 0, stream>>>(lnb, qkvbT, qkv_bb, Ttok, 3*D, D, 1, 0, 0, 0, qkvb, nullptr, nullptr, nullptr);
  attn_k<<<96 * 8, 256, 0, stream>>>(qkvb, attnb);
  gemm_bt<EPI_RESADD><<<g_proj, 256, 0, stream>>>(attnb, projbT, proj_bb, Ttok, D, D, 4, 0, 0, 0, nullptr, xf, nullptr, nullptr);
  gate_k<<<lnGrid, 256, 0, stream>>>(xf, ln2b_w, ln2b_b, gate_w, combine, Ttok);
  ln_k<<<lnGrid, 256, 0, stream>>>(xf, ln2b_w, ln2b_b, lnb, Ttok);
  for (int e = 0; e < 8; ++e) {
    transpose_k<<<dim3(HID/32, D/32, 1), tb, 0, stream>>>(w1 + (size_t)e*D*HID, wT, D, HID);
    gemm_bt<EPI_GELU><<<g_fc1, 256, 0, stream>>>(lnb, wT, b1 + (size_t)e*HID, Ttok, HID, D, 1, 0, 0, 0, h1, nullptr, nullptr, nullptr);
    transpose_k<<<dim3(D/32, HID/32, 1), tb, 0, stream>>>(w2 + (size_t)e*HID*D, wT, HID, D);
    gemm_bt<EPI_MOE><<<g_fc2, 256, 0, stream>>>(h1, wT, b2 + (size_t)e*D, Ttok, D, HID, 4, e, 0, 0, nullptr, xf, combine, nullptr);
  }

  // ---- per-task heads + masked aggregation (accumulate into out) ----
  f2b_k<<<(nTok + 255)/256, 256, 0, stream>>>(xf, lnb, nTok);
  gemm_bt<EPI_HEAD><<<g_head, 256, 0, stream>>>(lnb, headT, head_b, Ttok, D, D, 1, 0, (long long)D*D, D, nullptr, out, nullptr, valid);
  final_k<<<(nTok + 255)/256, 256, 0, stream>>>(out, cnt, nTok);
}

// Round 4
// 920.435 us; speedup vs baseline: 1.7344x; 1.7344x over previous
//
#include <hip/hip_runtime.h>
#include <hip/hip_bf16.h>

#define DEV static __device__ __forceinline__

typedef short bfx8 __attribute__((ext_vector_type(8)));   // 8 bf16 in 4 VGPRs (guide §3)
typedef float fx4  __attribute__((ext_vector_type(4)));

DEV float bf2f(__hip_bfloat16 h) { return __bfloat162float(h); }
DEV __hip_bfloat16 f2bf(float f) { return __float2bfloat16(f); }
DEV float uLO(unsigned u) { return __uint_as_float(u << 16); }
DEV float uHI(unsigned u) { return __uint_as_float(u & 0xffff0000u); }
DEV unsigned short f2bfu(float f) { __hip_bfloat16 h = __float2bfloat16(f); return *(unsigned short*)&h; }

DEV float wave_sum(float v) {
#pragma unroll
  for (int o = 32; o; o >>= 1) v += __shfl_xor(v, o, 64);
  return v;
}

#define GLD_LDS16(gp, lp) __builtin_amdgcn_global_load_lds( \
    (__attribute__((address_space(1))) void*)(gp),          \
    (__attribute__((address_space(3))) void*)(lp), 16, 0, 0)

// -------- transpose+convert: src fp32 [R][C] -> dst bf16 [C][R], batch z ----
__global__ __launch_bounds__(256) void transpose_k(
    const float* __restrict__ src, __hip_bfloat16* __restrict__ dst,
    int R, int C)
{
  __shared__ float tile[32][33];
  size_t off = (size_t)blockIdx.z * R * C;
  src += off; dst += off;
  int c0 = blockIdx.x * 32, r0 = blockIdx.y * 32;
#pragma unroll
  for (int i = 0; i < 32; i += 8)
    tile[threadIdx.y + i][threadIdx.x] =
        src[(size_t)(r0 + threadIdx.y + i) * C + c0 + threadIdx.x];
  __syncthreads();
#pragma unroll
  for (int i = 0; i < 32; i += 8)
    dst[(size_t)(c0 + threadIdx.y + i) * R + r0 + threadIdx.x] =
        f2bf(tile[threadIdx.x][threadIdx.y + i]);
}

// ---------------- GEMM: C = A[M,K] x B  (B given transposed: BT[N,K]) ------
// 128x128 tile, 4 waves, each wave 64x64 via 4x4 mfma_f32_16x16x32_bf16.
enum { EPI_STORE = 0, EPI_GELU = 1, EPI_RESADD = 2, EPI_MOE = 3, EPI_HEAD = 4 };

template <int MODE>
__global__ __launch_bounds__(256) void gemm_bt(
    const __hip_bfloat16* __restrict__ A,    // [M,K]  (+ zt*strideAz)
    const __hip_bfloat16* __restrict__ BT,   // [zt][N,K]
    const float* __restrict__ bias,          // [zt][N] fp32
    int M, int N, int K, int splitK, int taskBase,
    long long strideBz, long long strideBiasz, long long strideAz, long long strideCz,
    __hip_bfloat16* __restrict__ Cb, float* __restrict__ Cf,
    const float* __restrict__ combine, const int* __restrict__ valid)
{
  __shared__ __hip_bfloat16 sA[128 * 32];  // [m][k]
  __shared__ __hip_bfloat16 sB[128 * 32];  // [n][k]
  const int tid = threadIdx.x;
  const int wave = tid >> 6, lane = tid & 63;
  const int quad = lane >> 4, l16 = lane & 15;
  const int z = blockIdx.z;
  const int zt = z / splitK;
  const int kc = z - zt * splitK;
  const int task = taskBase + zt;
  const int Ksub = K / splitK;
  const int kbeg = kc * Ksub;
  A += (size_t)zt * strideAz;
  Cb += (size_t)zt * strideCz;
  const __hip_bfloat16* Bz = BT + (size_t)zt * strideBz;
  const float* biasz = bias + (size_t)zt * strideBiasz;
  const int m0 = blockIdx.y * 128, n0 = blockIdx.x * 128;
  const int wm = (wave >> 1) * 64, wn = (wave & 1) * 64;

  fx4 acc[4][4];
#pragma unroll
  for (int i = 0; i < 4; ++i)
#pragma unroll
    for (int j = 0; j < 4; ++j) acc[i][j] = (fx4){0.f, 0.f, 0.f, 0.f};

  // staging: chunk c covers row c>>2, k-seg (c&3)*8 ; LDS dest = c*8 elems
  // (wave-uniform base + lane*16B — matches m104/m108 constraint)
  const int c0 = tid, c1 = tid + 256;
  int gm0 = m0 + (c0 >> 2); if (gm0 > M - 1) gm0 = M - 1;
  int gm1 = m0 + (c1 >> 2); if (gm1 > M - 1) gm1 = M - 1;
  const int ak0 = (c0 & 3) * 8, ak1 = (c1 & 3) * 8;
  const __hip_bfloat16* pa0 = A + (size_t)gm0 * K + kbeg + ak0;
  const __hip_bfloat16* pa1 = A + (size_t)gm1 * K + kbeg + ak1;
  const __hip_bfloat16* pb0 = Bz + (size_t)(n0 + (c0 >> 2)) * K + kbeg + ak0;
  const __hip_bfloat16* pb1 = Bz + (size_t)(n0 + (c1 >> 2)) * K + kbeg + ak1;

  for (int kk = 0; kk < Ksub; kk += 32) {
    GLD_LDS16(pa0 + kk, &sA[c0 * 8]);
    GLD_LDS16(pa1 + kk, &sA[c1 * 8]);
    GLD_LDS16(pb0 + kk, &sB[c0 * 8]);
    GLD_LDS16(pb1 + kk, &sB[c1 * 8]);
    __syncthreads();   // drains vmcnt -> LDS writes visible
    bfx8 af[4], bfr[4];
#pragma unroll
    for (int i = 0; i < 4; ++i)
      af[i] = *(const bfx8*)(&sA[(wm + i * 16 + l16) * 32 + quad * 8]);
#pragma unroll
    for (int j = 0; j < 4; ++j)
      bfr[j] = *(const bfx8*)(&sB[(wn + j * 16 + l16) * 32 + quad * 8]);
#pragma unroll
    for (int i = 0; i < 4; ++i)
#pragma unroll
      for (int j = 0; j < 4; ++j)
        acc[i][j] = __builtin_amdgcn_mfma_f32_16x16x32_bf16(af[i], bfr[j], acc[i][j], 0, 0, 0);
    __syncthreads();
  }

  // epilogue: C/D layout col=lane&15, row=quad*4+reg (m89-verified)
  const int mb = m0 + wm + quad * 4;
  const int nb = n0 + wn + l16;
#pragma unroll
  for (int i = 0; i < 4; ++i) {
#pragma unroll
    for (int rr = 0; rr < 4; ++rr) {
      const int m = mb + i * 16 + rr;
      if (m >= M) continue;
#pragma unroll
      for (int j = 0; j < 4; ++j) {
        const int n = nb + j * 16;
        float v = acc[i][j][rr];
        if (MODE == EPI_STORE) {
          Cb[(size_t)m * N + n] = f2bf(v + biasz[n]);
        } else if (MODE == EPI_GELU) {
          float t = v + biasz[n];
          Cb[(size_t)m * N + n] = f2bf(0.5f * t * (1.f + erff(t * 0.70710678118654752f)));
        } else if (MODE == EPI_RESADD) {
          if (kc == 0) v += biasz[n];
          atomicAdd(&Cf[(size_t)m * N + n], v);
        } else if (MODE == EPI_MOE) {
          float s = combine[m * 8 + task];
          if (s != 0.f) {
            if (kc == 0) v += biasz[n];
            atomicAdd(&Cf[(size_t)m * N + n], s * v);
          }
        } else {  // EPI_HEAD
          if (valid[task * M + m]) atomicAdd(&Cf[(size_t)m * N + n], v + biasz[n]);
        }
      }
    }
  }
}

// ---------------- MFMA attention ------------------------------------------
// grid.x = B*H*4 ; block = 256. Each wave owns one 16-row m-tile of S (13 tiles).
// QK^T: A/B frags straight from global (rows are k-contiguous).
// Softmax in regs (16-lane shuffle). P -> LDS strip (bf16 hi+lo compensated,
// two PV passes over the same strip — same-wave ordering, no barrier).
__global__ __launch_bounds__(256) void attn_mfma_k(
    const __hip_bfloat16* __restrict__ qkvb, __hip_bfloat16* __restrict__ outb)
{
  __shared__ __align__(16) unsigned short VT[64 * 232];       // V^T [d][tok], stride 232
  __shared__ __align__(16) unsigned short Pst[4][16 * 232];   // per-wave P strip [m][tok]
  const int tid = threadIdx.x;
  const int chunk = blockIdx.x & 3;
  const int bh = blockIdx.x >> 2;
  const int b = bh / 12, h = bh - b * 12;
  const size_t tokBase = (size_t)b * 197;
  const __hip_bfloat16* qkvh = qkvb + tokBase * 2304 + (size_t)h * 64;

  // stage V^T (which=2 -> +1536)
  for (int idx = tid; idx < 197 * 32; idx += 256) {
    int j = idx >> 5, dp = idx & 31;
    unsigned pv = *(const unsigned*)(qkvh + (size_t)j * 2304 + 1536 + dp * 2);
    VT[(2 * dp) * 232 + j]     = (unsigned short)(pv & 0xffffu);
    VT[(2 * dp + 1) * 232 + j] = (unsigned short)(pv >> 16);
  }
  // NaN fix: zero VT pad cols [197,232). PV reads cols up to 223; leftover LDS
  // bits there can be Inf/NaN-pattern bf16, and 0 (from P) * Inf = NaN.
  for (int idx = tid; idx < 64 * 35; idx += 256) {
    int r = idx / 35, c = 197 + idx % 35;
    VT[r * 232 + c] = 0;
  }
  __syncthreads();

  const int wave = tid >> 6, lane = tid & 63;
  const int quad = lane >> 4, l16 = lane & 15;
  const int mt = chunk * 4 + wave;   // m-tile 0..12
  if (mt >= 13) return;

  // zero P strip pad cols [208,224)
  {
    int r = lane >> 2, c = 208 + (lane & 3) * 4;
    *(uint2*)&Pst[wave][r * 232 + c] = (uint2){0u, 0u};
  }

  // Q A-frags (clamped rows; invalid rows computed but never stored)
  int tq = mt * 16 + l16; if (tq > 196) tq = 196;
  const bfx8 af0 = *(const bfx8*)(qkvh + (size_t)tq * 2304 + quad * 8);
  const bfx8 af1 = *(const bfx8*)(qkvh + (size_t)tq * 2304 + 32 + quad * 8);

  // S strip: 13 n-tiles, K frags from global (which=1 -> +768)
  fx4 sv[13];
#pragma unroll
  for (int n0 = 0; n0 < 13; ++n0) {
    int tk = n0 * 16 + l16; if (tk > 196) tk = 196;
    const __hip_bfloat16* kp = qkvh + (size_t)tk * 2304 + 768;
    bfx8 bf0 = *(const bfx8*)(kp + quad * 8);
    bfx8 bf1 = *(const bfx8*)(kp + 32 + quad * 8);
    fx4 a = (fx4){0.f, 0.f, 0.f, 0.f};
    a = __builtin_amdgcn_mfma_f32_16x16x32_bf16(af0, bf0, a, 0, 0, 0);
    a = __builtin_amdgcn_mfma_f32_16x16x32_bf16(af1, bf1, a, 0, 0, 0);
    sv[n0] = a;
  }

  // softmax per row (row = quad*4+rr); cols of lane: n0*16+l16
  float inv[4];
#pragma unroll
  for (int rr = 0; rr < 4; ++rr) {
    float mx = -3.0e38f;
#pragma unroll
    for (int n0 = 0; n0 < 13; ++n0) {
      bool ok = (n0 < 12) | (l16 < 5);           // col < 197
      float s = ok ? sv[n0][rr] * 0.125f : -3.0e38f;
      sv[n0][rr] = s;
      mx = fmaxf(mx, s);
    }
#pragma unroll
    for (int o = 1; o < 16; o <<= 1) mx = fmaxf(mx, __shfl_xor(mx, o, 64));
    float sum = 0.f;
#pragma unroll
    for (int n0 = 0; n0 < 13; ++n0) {
      float s = sv[n0][rr];
      float e = (s > -1.0e38f) ? __expf(s - mx) : 0.f;
      sv[n0][rr] = e;
      sum += e;
    }
#pragma unroll
    for (int o = 1; o < 16; o <<= 1) sum += __shfl_xor(sum, o, 64);
    inv[rr] = 1.f / sum;
    const int row = quad * 4 + rr;
#pragma unroll
    for (int n0 = 0; n0 < 13; ++n0)
      Pst[wave][row * 232 + n0 * 16 + l16] = f2bfu(sv[n0][rr]);   // P hi
  }

  // PV pass 1 (P hi)
  fx4 pv[4];
#pragma unroll
  for (int nd = 0; nd < 4; ++nd) pv[nd] = (fx4){0.f, 0.f, 0.f, 0.f};
#pragma unroll
  for (int kk = 0; kk < 7; ++kk) {
    bfx8 paf = *(const bfx8*)&Pst[wave][l16 * 232 + kk * 32 + quad * 8];
#pragma unroll
    for (int nd = 0; nd < 4; ++nd) {
      bfx8 bfv = *(const bfx8*)&VT[(nd * 16 + l16) * 232 + kk * 32 + quad * 8];
      pv[nd] = __builtin_amdgcn_mfma_f32_16x16x32_bf16(paf, bfv, pv[nd], 0, 0, 0);
    }
  }

  // P lo = e - bf16(e), overwrite same strip (same-wave ordering -> safe)
#pragma unroll
  for (int rr = 0; rr < 4; ++rr) {
    const int row = quad * 4 + rr;
#pragma unroll
    for (int n0 = 0; n0 < 13; ++n0) {
      float e = sv[n0][rr];
      Pst[wave][row * 232 + n0 * 16 + l16] = f2bfu(e - uLO(f2bfu(e)));
    }
  }

  // PV pass 2 (P lo) accumulates
#pragma unroll
  for (int kk = 0; kk < 7; ++kk) {
    bfx8 paf = *(const bfx8*)&Pst[wave][l16 * 232 + kk * 32 + quad * 8];
#pragma unroll
    for (int nd = 0; nd < 4; ++nd) {
      bfx8 bfv = *(const bfx8*)&VT[(nd * 16 + l16) * 232 + kk * 32 + quad * 8];
      pv[nd] = __builtin_amdgcn_mfma_f32_16x16x32_bf16(paf, bfv, pv[nd], 0, 0, 0);
    }
  }

  // store: row m = mt*16 + quad*4 + rr, col d = nd*16 + l16
#pragma unroll
  for (int rr = 0; rr < 4; ++rr) {
    int m = mt * 16 + quad * 4 + rr;
    if (m > 196) continue;
    __hip_bfloat16* op = outb + (tokBase + m) * 768 + (size_t)h * 64;
#pragma unroll
    for (int nd = 0; nd < 4; ++nd)
      op[nd * 16 + l16] = f2bf(pv[nd][rr] * inv[rr]);
  }
}

// ---------------- LayerNorm: one wave per token, fp32 in -> bf16 out -------
__global__ __launch_bounds__(256) void ln_k(
    const float* __restrict__ xf, const float* __restrict__ w,
    const float* __restrict__ b, __hip_bfloat16* __restrict__ out, int T)
{
  int wv = threadIdx.x >> 6, lane = threadIdx.x & 63;
  int t = blockIdx.x * 4 + wv;
  if (t >= T) return;
  const float* row = xf + (size_t)t * 768;
  float v[12]; float s = 0.f;
#pragma unroll
  for (int i = 0; i < 12; ++i) { v[i] = row[lane + i * 64]; s += v[i]; }
  s = wave_sum(s);
  float mean = s * (1.f / 768.f);
  float q = 0.f;
#pragma unroll
  for (int i = 0; i < 12; ++i) { float d = v[i] - mean; q += d * d; }
  q = wave_sum(q);
  float rstd = rsqrtf(q * (1.f / 768.f) + 1e-5f);
#pragma unroll
  for (int i = 0; i < 12; ++i) {
    int d = lane + i * 64;
    out[(size_t)t * 768 + d] = f2bf((v[i] - mean) * rstd * w[d] + b[d]);
  }
}

// ---------------- MoE gating: fp32 LN + logits + softmax + top-4 ----------
__global__ __launch_bounds__(256) void gate_k(
    const float* __restrict__ xf, const float* __restrict__ lw,
    const float* __restrict__ lb, const float* __restrict__ gw,
    float* __restrict__ combine, int T)
{
  int wv = threadIdx.x >> 6, lane = threadIdx.x & 63;
  int t = blockIdx.x * 4 + wv;
  if (t >= T) return;
  const float* row = xf + (size_t)t * 768;
  float v[12]; float s = 0.f;
#pragma unroll
  for (int i = 0; i < 12; ++i) { v[i] = row[lane + i * 64]; s += v[i]; }
  s = wave_sum(s);
  float mean = s * (1.f / 768.f);
  float qv = 0.f;
#pragma unroll
  for (int i = 0; i < 12; ++i) { float d = v[i] - mean; qv += d * d; }
  qv = wave_sum(qv);
  float rstd = rsqrtf(qv * (1.f / 768.f) + 1e-5f);
  float acc[8];
#pragma unroll
  for (int e = 0; e < 8; ++e) acc[e] = 0.f;
#pragma unroll
  for (int i = 0; i < 12; ++i) {
    int d = lane + i * 64;
    float xn = (v[i] - mean) * rstd * lw[d] + lb[d];
    float4 g0 = *(const float4*)(gw + (size_t)d * 8);
    float4 g1 = *(const float4*)(gw + (size_t)d * 8 + 4);
    acc[0] += xn * g0.x; acc[1] += xn * g0.y;
    acc[2] += xn * g0.z; acc[3] += xn * g0.w;
    acc[4] += xn * g1.x; acc[5] += xn * g1.y;
    acc[6] += xn * g1.z; acc[7] += xn * g1.w;
  }
#pragma unroll
  for (int e = 0; e < 8; ++e) acc[e] = wave_sum(acc[e]);
  float mx = acc[0];
#pragma unroll
  for (int e = 1; e < 8; ++e) mx = fmaxf(mx, acc[e]);
  float p[8]; float se = 0.f;
#pragma unroll
  for (int e = 0; e < 8; ++e) { p[e] = __expf(acc[e] - mx); se += p[e]; }
  float inv = 1.f / se;
#pragma unroll
  for (int e = 0; e < 8; ++e) p[e] *= inv;
  float outv[8]; bool used[8];
#pragma unroll
  for (int e = 0; e < 8; ++e) { outv[e] = 0.f; used[e] = false; }
  for (int k = 0; k < 4; ++k) {   // top-4, ties -> lowest index (matches top_k)
    int best = -1; float bv = -1.f;
#pragma unroll
    for (int e = 0; e < 8; ++e) if (!used[e] && p[e] > bv) { bv = p[e]; best = e; }
#pragma unroll
    for (int e = 0; e < 8; ++e) if (e == best) { used[e] = true; outv[e] = bv; }
  }
#pragma unroll
  for (int e = 0; e < 8; ++e) if (lane == e) combine[(size_t)t * 8 + e] = outv[e];
}

// ---------------- masks / small utils --------------------------------------
__global__ void mask_k(const int* __restrict__ sm, const int* __restrict__ am,
                       float* __restrict__ cnt, int* __restrict__ valid, int T)
{
  int t = blockIdx.x * 256 + threadIdx.x;
  if (t >= T) return;
  int a = am[t] != 0;
  float c = 0.f;
#pragma unroll
  for (int tt = 0; tt < 8; ++tt) {
    int vv = (sm[tt * T + t] != 0) & a;
    valid[tt * T + t] = vv;
    c += (float)vv;
  }
  cnt[t] = c;
}

__global__ void f2b_k(const float* __restrict__ in, __hip_bfloat16* __restrict__ out, int n) {
  int i = blockIdx.x * 256 + threadIdx.x;
  if (i < n) out[i] = f2bf(in[i]);
}
// in-place: out[i] = out[i] / (cnt[i/768] + 1e-6)
__global__ void final_k(float* __restrict__ out, const float* __restrict__ cnt, int n) {
  int i = blockIdx.x * 256 + threadIdx.x;
  if (i < n) out[i] = out[i] / (cnt[i / 768] + 1e-6f);
}

// ---------------- host ------------------------------------------------------
extern "C" void kernel_launch(void* const* d_in, const int* in_sizes, int n_in,
                              void* d_out, int out_size, void* d_ws, size_t ws_size,
                              hipStream_t stream)
{
  (void)in_sizes; (void)n_in; (void)out_size;
  const int Ttok = 8 * 197;  // 1576
  const int D = 768, HID = 3072;

  const float* x       = (const float*)d_in[0];
  const float* ln1a_w  = (const float*)d_in[1];
  const float* ln1a_b  = (const float*)d_in[2];
  const float* qkv_wa  = (const float*)d_in[3];
  const float* qkv_ba  = (const float*)d_in[4];
  const float* proj_wa = (const float*)d_in[5];
  const float* proj_ba = (const float*)d_in[6];
  const float* ln2a_w  = (const float*)d_in[7];
  const float* ln2a_b  = (const float*)d_in[8];
  const float* fc1_w   = (const float*)d_in[9];
  const float* fc1_b   = (const float*)d_in[10];
  const float* fc2_w   = (const float*)d_in[11];
  const float* fc2_b   = (const float*)d_in[12];
  const float* ln1b_w  = (const float*)d_in[13];
  const float* ln1b_b  = (const float*)d_in[14];
  const float* qkv_wb  = (const float*)d_in[15];
  const float* qkv_bb  = (const float*)d_in[16];
  const float* proj_wb = (const float*)d_in[17];
  const float* proj_bb = (const float*)d_in[18];
  const float* ln2b_w  = (const float*)d_in[19];
  const float* ln2b_b  = (const float*)d_in[20];
  const float* gate_w  = (const float*)d_in[21];
  const float* w1      = (const float*)d_in[22];
  const float* b1      = (const float*)d_in[23];
  const float* w2      = (const float*)d_in[24];
  const float* b2      = (const float*)d_in[25];
  const float* head_w  = (const float*)d_in[26];
  const float* head_b  = (const float*)d_in[27];
  const int* shared_masks = (const int*)d_in[28];
  const int* agg_mask     = (const int*)d_in[29];
  float* out           = (float*)d_out;

  char* wsp = (char*)d_ws;
  auto alloc = [&](size_t bytes) { char* p = wsp; wsp += (bytes + 255) & ~(size_t)255; return p; };
  float* xf             = (float*)alloc((size_t)Ttok * D * 4);
  __hip_bfloat16* lnb   = (__hip_bfloat16*)alloc((size_t)Ttok * D * 2);
  __hip_bfloat16* qkvb  = (__hip_bfloat16*)alloc((size_t)Ttok * 3 * D * 2);
  __hip_bfloat16* attnb = (__hip_bfloat16*)alloc((size_t)Ttok * D * 2);
  __hip_bfloat16* h1    = (__hip_bfloat16*)alloc((size_t)Ttok * HID * 2);
  float* combine        = (float*)alloc((size_t)Ttok * 8 * 4);
  float* cnt            = (float*)alloc((size_t)Ttok * 4);
  int* valid            = (int*)alloc((size_t)8 * Ttok * 4);
  __hip_bfloat16* qkvaT = (__hip_bfloat16*)alloc((size_t)D * 3 * D * 2);
  __hip_bfloat16* projaT= (__hip_bfloat16*)alloc((size_t)D * D * 2);
  __hip_bfloat16* fc1T  = (__hip_bfloat16*)alloc((size_t)D * HID * 2);
  __hip_bfloat16* fc2T  = (__hip_bfloat16*)alloc((size_t)D * HID * 2);
  __hip_bfloat16* qkvbT = (__hip_bfloat16*)alloc((size_t)D * 3 * D * 2);
  __hip_bfloat16* projbT= (__hip_bfloat16*)alloc((size_t)D * D * 2);
  __hip_bfloat16* headT = (__hip_bfloat16*)alloc((size_t)8 * D * D * 2);
  __hip_bfloat16* wT    = (__hip_bfloat16*)alloc((size_t)D * HID * 2);

  // batched-MoE extra buffers (deterministic guard: ws_size constant per harness)
  const size_t used = (size_t)(wsp - (char*)d_ws);
  const size_t extraNeed = 2 * ((size_t)8 * D * HID * 2 + 255)        // w1T8 + w2T8
                         + ((size_t)8 * Ttok * HID * 2 + 255);        // h1_8
  const bool batched = (ws_size >= used + extraNeed);
  __hip_bfloat16* w1T8 = nullptr; __hip_bfloat16* w2T8 = nullptr; __hip_bfloat16* h1_8 = nullptr;
  if (batched) {
    w1T8 = (__hip_bfloat16*)alloc((size_t)8 * D * HID * 2);
    w2T8 = (__hip_bfloat16*)alloc((size_t)8 * D * HID * 2);
    h1_8 = (__hip_bfloat16*)alloc((size_t)8 * Ttok * HID * 2);
  }

  dim3 tb(32, 8);
  transpose_k<<<dim3(3*D/32, D/32, 1), tb, 0, stream>>>(qkv_wa, qkvaT, D, 3*D);
  transpose_k<<<dim3(D/32, D/32, 1),   tb, 0, stream>>>(proj_wa, projaT, D, D);
  transpose_k<<<dim3(HID/32, D/32, 1), tb, 0, stream>>>(fc1_w, fc1T, D, HID);
  transpose_k<<<dim3(D/32, HID/32, 1), tb, 0, stream>>>(fc2_w, fc2T, HID, D);
  transpose_k<<<dim3(3*D/32, D/32, 1), tb, 0, stream>>>(qkv_wb, qkvbT, D, 3*D);
  transpose_k<<<dim3(D/32, D/32, 1),   tb, 0, stream>>>(proj_wb, projbT, D, D);
  transpose_k<<<dim3(D/32, D/32, 8),   tb, 0, stream>>>(head_w, headT, D, D);
  if (batched) {
    transpose_k<<<dim3(HID/32, D/32, 8), tb, 0, stream>>>(w1, w1T8, D, HID);
    transpose_k<<<dim3(D/32, HID/32, 8), tb, 0, stream>>>(w2, w2T8, HID, D);
  }

  const int nTok = Ttok * D;
  hipMemcpyAsync(xf, x, (size_t)nTok * 4, hipMemcpyDeviceToDevice, stream);
  mask_k<<<(Ttok + 255)/256, 256, 0, stream>>>(shared_masks, agg_mask, cnt, valid, Ttok);
  hipMemsetAsync(out, 0, (size_t)nTok * 4, stream);  // head accumulation buffer

  const int lnGrid = (Ttok + 3) / 4;
  dim3 g_qkv(3*D/128, 13, 1);
  dim3 g_proj(D/128, 13, 4);    // split-K x4
  dim3 g_fc1(HID/128, 13, 1);
  dim3 g_fc2(D/128, 13, 4);     // split-K x4
  dim3 g_head(D/128, 13, 8);    // z = task
  const int attnGrid = 96 * 4;  // (b,h) x 4 row-chunks

  // ---- dense ViT block ----
  ln_k<<<lnGrid, 256, 0, stream>>>(xf, ln1a_w, ln1a_b, lnb, Ttok);
  gemm_bt<EPI_STORE><<<g_qkv, 256, 0, stream>>>(lnb, qkvaT, qkv_ba, Ttok, 3*D, D, 1, 0, 0, 0, 0, 0, qkvb, nullptr, nullptr, nullptr);
  attn_mfma_k<<<attnGrid, 256, 0, stream>>>(qkvb, attnb);
  gemm_bt<EPI_RESADD><<<g_proj, 256, 0, stream>>>(attnb, projaT, proj_ba, Ttok, D, D, 4, 0, 0, 0, 0, 0, nullptr, xf, nullptr, nullptr);
  ln_k<<<lnGrid, 256, 0, stream>>>(xf, ln2a_w, ln2a_b, lnb, Ttok);
  gemm_bt<EPI_GELU><<<g_fc1, 256, 0, stream>>>(lnb, fc1T, fc1_b, Ttok, HID, D, 1, 0, 0, 0, 0, 0, h1, nullptr, nullptr, nullptr);
  gemm_bt<EPI_RESADD><<<g_fc2, 256, 0, stream>>>(h1, fc2T, fc2_b, Ttok, D, HID, 4, 0, 0, 0, 0, 0, nullptr, xf, nullptr, nullptr);

  // ---- MoE ViT block ----
  ln_k<<<lnGrid, 256, 0, stream>>>(xf, ln1b_w, ln1b_b, lnb, Ttok);
  gemm_bt<EPI_STORE><<<g_qkv, 256, 0, stream>>>(lnb, qkvbT, qkv_bb, Ttok, 3*D, D, 1, 0, 0, 0, 0, 0, qkvb, nullptr, nullptr, nullptr);
  attn_mfma_k<<<attnGrid, 256, 0, stream>>>(qkvb, attnb);
  gemm_bt<EPI_RESADD><<<g_proj, 256, 0, stream>>>(attnb, projbT, proj_bb, Ttok, D, D, 4, 0, 0, 0, 0, 0, nullptr, xf, nullptr, nullptr);
  gate_k<<<lnGrid, 256, 0, stream>>>(xf, ln2b_w, ln2b_b, gate_w, combine, Ttok);
  ln_k<<<lnGrid, 256, 0, stream>>>(xf, ln2b_w, ln2b_b, lnb, Ttok);
  if (batched) {
    gemm_bt<EPI_GELU><<<dim3(HID/128, 13, 8), 256, 0, stream>>>(
        lnb, w1T8, b1, Ttok, HID, D, 1, 0,
        (long long)D*HID, HID, 0, (long long)Ttok*HID, h1_8, nullptr, nullptr, nullptr);
    gemm_bt<EPI_MOE><<<dim3(D/128, 13, 32), 256, 0, stream>>>(
        h1_8, w2T8, b2, Ttok, D, HID, 4, 0,
        (long long)HID*D, D, (long long)Ttok*HID, 0, nullptr, xf, combine, nullptr);
  } else {
    for (int e = 0; e < 8; ++e) {
      transpose_k<<<dim3(HID/32, D/32, 1), tb, 0, stream>>>(w1 + (size_t)e*D*HID, wT, D, HID);
      gemm_bt<EPI_GELU><<<g_fc1, 256, 0, stream>>>(lnb, wT, b1 + (size_t)e*HID, Ttok, HID, D, 1, 0, 0, 0, 0, 0, h1, nullptr, nullptr, nullptr);
      transpose_k<<<dim3(D/32, HID/32, 1), tb, 0, stream>>>(w2 + (size_t)e*HID*D, wT, HID, D);
      gemm_bt<EPI_MOE><<<g_fc2, 256, 0, stream>>>(h1, wT, b2 + (size_t)e*D, Ttok, D, HID, 4, e, 0, 0, 0, 0, nullptr, xf, combine, nullptr);
    }
  }

  // ---- per-task heads + masked aggregation (accumulate into out) ----
  f2b_k<<<(nTok + 255)/256, 256, 0, stream>>>(xf, lnb, nTok);
  gemm_bt<EPI_HEAD><<<g_head, 256, 0, stream>>>(lnb, headT, head_b, Ttok, D, D, 1, 0, (long long)D*D, D, 0, 0, nullptr, out, nullptr, valid);
  final_k<<<(nTok + 255)/256, 256, 0, stream>>>(out, cnt, nTok);
}